// Round 3
// baseline (221.425 us; speedup 1.0000x reference)
//
#include <hip/hip_runtime.h>
#include <hip/hip_bf16.h>

// RhymeLoss: mean over b in [0,4096), pairs i<j in [0,32) of
//   same(i,j) ? 1 - cos(u_i,u_j) : relu(cos(u_i,u_j) - 0.5)
// One wave per batch. Gram G = U U^T via mfma_f32_16x16x32_bf16, fragments
// loaded straight from global (A-frag == B-frag for a gram), norms from the
// gram diagonal, loss epilogue, atomicAdd of scaled partials.
//
// R3 change: __builtin_amdgcn_sched_barrier(0) between the load phase and the
// convert/MFMA phase. R2 tried source-level preloading but the compiler SANK
// the loads back into the consume loop (VGPR_Count=48 proved it) and stayed
// latency-bound at ~10% HBM BW. The sched_barrier pins all 32
// global_load_dwordx4 above every use -> 32 KiB in flight per wave.
// Expected cost: VGPR ~170-190 -> 2 waves/SIMD (8/CU). That is plenty:
// Little's law needs only ~3-9 KiB/CU in flight to saturate HBM.

typedef short bf16x8 __attribute__((ext_vector_type(8)));   // 8 bf16 in 4 VGPRs
typedef float f32x4  __attribute__((ext_vector_type(4)));

#define MARGIN 0.5f
#define EPS_NORM 1e-8f
#define NPAIR_INV (1.0f / 2031616.0f)   // 1 / (4096 * 496)

// fp32 -> bf16 round-to-nearest-even (inputs are finite, no NaN handling)
static __device__ __forceinline__ short f2bf(float f) {
    unsigned u = __float_as_uint(f);
    u += 0x7fffu + ((u >> 16) & 1u);
    return (short)(u >> 16);
}

__global__ __launch_bounds__(256) void rhyme_loss_kernel(
    const float* __restrict__ emb,   // [4096][32][256] fp32
    const int*   __restrict__ sch,   // [4096][32] int32
    float*       __restrict__ out)   // [1] fp32 (pre-zeroed)
{
    __shared__ float s_diag[4][32];
    __shared__ float s_inv[4][32];
    __shared__ int   s_sch[4][32];

    const int tid  = threadIdx.x;
    const int w    = tid >> 6;            // wave id within block, 0..3
    const int lane = tid & 63;
    const int b    = blockIdx.x * 4 + w;  // batch index, one wave per batch

    const int q = lane >> 4;              // quad 0..3 -> k-offset q*8
    const int c = lane & 15;              // fragment row (= C col)

    // Lane's global source: row c (frag0) / row 16+c (frag1), cols kc+q*8..+7
    const float* base0 = emb + (size_t)b * 8192 + (size_t)c * 256 + q * 8;
    const float* base1 = base0 + 16 * 256;

    // ---- Phase 1: issue every load up front (32 x dwordx4 in flight) ----
    float4 ra[16];   // frag0 data: chunk kc8 -> ra[2*kc8], ra[2*kc8+1]
    float4 rb[16];   // frag1 data
    #pragma unroll
    for (int kc8 = 0; kc8 < 8; ++kc8) {
        const float4* p0 = (const float4*)(base0 + kc8 * 32);
        const float4* p1 = (const float4*)(base1 + kc8 * 32);
        ra[2 * kc8]     = p0[0];
        ra[2 * kc8 + 1] = p0[1];
        rb[2 * kc8]     = p1[0];
        rb[2 * kc8 + 1] = p1[1];
    }

    // Hard scheduling fence: nothing crosses. Keeps all 32 loads issued
    // back-to-back before any consume -> full-batch MLP per wave.
    __builtin_amdgcn_sched_barrier(0);

    f32x4 acc00 = {0.f, 0.f, 0.f, 0.f};   // rows 0-15  x cols 0-15
    f32x4 acc01 = {0.f, 0.f, 0.f, 0.f};   // rows 0-15  x cols 16-31
    f32x4 acc11 = {0.f, 0.f, 0.f, 0.f};   // rows 16-31 x cols 16-31
    // (tile 10 is the i>j mirror of 01 -> never needed)

    // ---- Phase 2: convert + MFMA (consumes in issue order -> compiler can
    // use fine-grained vmcnt(N) and overlap with in-flight loads) ----
    #pragma unroll
    for (int kc8 = 0; kc8 < 8; ++kc8) {
        float4 a0 = ra[2 * kc8], a1 = ra[2 * kc8 + 1];
        float4 b0 = rb[2 * kc8], b1 = rb[2 * kc8 + 1];

        bf16x8 f0, f1;
        f0[0] = f2bf(a0.x); f0[1] = f2bf(a0.y); f0[2] = f2bf(a0.z); f0[3] = f2bf(a0.w);
        f0[4] = f2bf(a1.x); f0[5] = f2bf(a1.y); f0[6] = f2bf(a1.z); f0[7] = f2bf(a1.w);
        f1[0] = f2bf(b0.x); f1[1] = f2bf(b0.y); f1[2] = f2bf(b0.z); f1[3] = f2bf(b0.w);
        f1[4] = f2bf(b1.x); f1[5] = f2bf(b1.y); f1[6] = f2bf(b1.z); f1[7] = f2bf(b1.w);

        // A-frag and B-frag of a gram share the same per-lane data.
        acc00 = __builtin_amdgcn_mfma_f32_16x16x32_bf16(f0, f0, acc00, 0, 0, 0);
        acc01 = __builtin_amdgcn_mfma_f32_16x16x32_bf16(f0, f1, acc01, 0, 0, 0);
        acc11 = __builtin_amdgcn_mfma_f32_16x16x32_bf16(f1, f1, acc11, 0, 0, 0);
    }

    // C/D layout (m89-verified): col = lane&15, row = (lane>>4)*4 + reg.
    // Diagonal of tiles 00/11: row==col -> reg = c - 4*q when in [0,4).
    const int dreg = c - 4 * q;
    if (dreg >= 0 && dreg < 4) {
        s_diag[w][c]      = acc00[dreg];   // ||u_c||^2
        s_diag[w][16 + c] = acc11[dreg];   // ||u_{16+c}||^2
    }
    __syncthreads();

    if (lane < 32) {
        float d = s_diag[w][lane];
        s_inv[w][lane] = 1.0f / fmaxf(sqrtf(d), EPS_NORM);
        s_sch[w][lane] = sch[b * 32 + lane];
    }
    __syncthreads();

    const float invj0 = s_inv[w][c];
    const float invj1 = s_inv[w][16 + c];
    const int   sj0   = s_sch[w][c];
    const int   sj1   = s_sch[w][16 + c];

    float sum = 0.0f;
    #pragma unroll
    for (int r = 0; r < 4; ++r) {
        const int   i0    = q * 4 + r;
        const float inv_i = s_inv[w][i0];
        const int   si    = s_sch[w][i0];

        // tile 01: i = i0 (<16), j = 16+c  -> always i<j
        {
            float sim = acc01[r] * inv_i * invj1;
            sum += (si == sj1) ? (1.0f - sim) : fmaxf(sim - MARGIN, 0.0f);
        }
        if (i0 < c) {
            // tile 00: i = i0, j = c
            float sim = acc00[r] * inv_i * invj0;
            sum += (si == sj0) ? (1.0f - sim) : fmaxf(sim - MARGIN, 0.0f);
            // tile 11: i = 16+i0, j = 16+c
            float sim2 = acc11[r] * s_inv[w][16 + i0] * invj1;
            sum += (s_sch[w][16 + i0] == sj1) ? (1.0f - sim2)
                                              : fmaxf(sim2 - MARGIN, 0.0f);
        }
    }

    // wave-64 reduction
    #pragma unroll
    for (int off = 32; off > 0; off >>= 1)
        sum += __shfl_down(sum, off, 64);

    if (lane == 0)
        atomicAdd(out, sum * NPAIR_INV);
}

extern "C" void kernel_launch(void* const* d_in, const int* in_sizes, int n_in,
                              void* d_out, int out_size, void* d_ws, size_t ws_size,
                              hipStream_t stream) {
    const float* emb = (const float*)d_in[0];
    const int*   sch = (const int*)d_in[1];
    float*       out = (float*)d_out;

    hipMemsetAsync(out, 0, sizeof(float), stream);   // d_out is poisoned 0xAA
    rhyme_loss_kernel<<<dim3(4096 / 4), dim3(256), 0, stream>>>(emb, sch, out);
}

// Round 4
// 211.950 us; speedup vs baseline: 1.0447x; 1.0447x over previous
//
#include <hip/hip_runtime.h>
#include <hip/hip_bf16.h>
#include <stdint.h>

// RhymeLoss: mean over b in [0,4096), pairs i<j in [0,32) of
//   same(i,j) ? 1 - cos(u_i,u_j) : relu(cos(u_i,u_j) - 0.5)
//
// R4 structure: one WAVE per batch, one wave per block (64 threads).
//  - Stage the batch's 32 rows (32 KiB fp32) into LDS via 32
//    __builtin_amdgcn_global_load_lds(16B/lane) DMAs. No dest VGPRs ->
//    the compiler CANNOT sink these (R2/R3 showed VGPR preloads get
//    re-interleaved; VGPR_Count stayed 48 and we sat latency-bound at
//    1.66 TB/s). Each DMA reads one fully-contiguous 1 KiB row (TA fast
//    path) instead of the 16-line row-strided gather of R1-R3.
//  - Rows stored at stride 260 floats (pad 4): fragment ds_read_b128
//    start-bank = (4c+8q)%32 -> uniform 8 touches/bank (b128 minimum).
//  - Then convert fp32->bf16 and run the same 3-tile gram MFMA
//    (A-frag == B-frag), norms from the gram diagonal, loss epilogue,
//    one atomicAdd per wave.

typedef short bf16x8 __attribute__((ext_vector_type(8)));   // 8 bf16 in 4 VGPRs
typedef float f32x4  __attribute__((ext_vector_type(4)));

#define MARGIN 0.5f
#define EPS_NORM 1e-8f
#define NPAIR_INV (1.0f / 2031616.0f)   // 1 / (4096 * 496)
#define ROW_STRIDE 260                  // floats; +4 pad for LDS bank spread

typedef const __attribute__((address_space(1))) void GVOID;
typedef __attribute__((address_space(3))) void LVOID;

// fp32 -> bf16 round-to-nearest-even (inputs are finite, no NaN handling)
static __device__ __forceinline__ short f2bf(float f) {
    unsigned u = __float_as_uint(f);
    u += 0x7fffu + ((u >> 16) & 1u);
    return (short)(u >> 16);
}

__global__ __launch_bounds__(64) void rhyme_loss_kernel(
    const float* __restrict__ emb,   // [4096][32][256] fp32
    const int*   __restrict__ sch,   // [4096][32] int32
    float*       __restrict__ out)   // [1] fp32 (pre-zeroed)
{
    __shared__ float s_rows[32 * ROW_STRIDE];   // 33,280 B
    __shared__ float s_inv[32];
    __shared__ float s_diag[32];
    __shared__ int   s_sch[32];

    const int lane = threadIdx.x;        // 0..63 (one wave per block)
    const int b    = blockIdx.x;         // batch index

    const int q = lane >> 4;             // quad 0..3 -> k-offset q*8
    const int c = lane & 15;             // fragment row (= C col)

    // ---- Phase 1: 32 fire-and-forget row DMAs (32 KiB in flight) ----
    // Row r: lanes read emb[b][r][lane*4 .. lane*4+3] (contiguous 1 KiB),
    // land at s_rows + r*ROW_STRIDE + lane*4 (wave-uniform base + lane*16B).
    const float* gbase = emb + (size_t)b * 8192 + (size_t)lane * 4;
    #pragma unroll
    for (int r = 0; r < 32; ++r) {
        __builtin_amdgcn_global_load_lds(
            (GVOID*)(gbase + r * 256),
            (LVOID*)(&s_rows[r * ROW_STRIDE]),
            16, 0, 0);
    }

    // Independent scheme load overlaps the DMA latency.
    int mysch = (lane < 32) ? sch[(size_t)b * 32 + lane] : 0;

    // Drain the DMAs (vmcnt tracks global_load_lds), then barrier for LDS
    // visibility ordering. Single-wave block -> barrier is nearly free.
    __builtin_amdgcn_s_waitcnt(0x0f70);  // vmcnt(0), exp/lgkm unconstrained
    __syncthreads();

    if (lane < 32) s_sch[lane] = mysch;

    // ---- Phase 2: fragments from LDS, convert, 3-tile gram MFMA ----
    const float* r0 = s_rows + (size_t)c * ROW_STRIDE + q * 8;         // row c
    const float* r1 = s_rows + (size_t)(16 + c) * ROW_STRIDE + q * 8;  // row 16+c

    f32x4 acc00 = {0.f, 0.f, 0.f, 0.f};   // rows 0-15  x cols 0-15
    f32x4 acc01 = {0.f, 0.f, 0.f, 0.f};   // rows 0-15  x cols 16-31
    f32x4 acc11 = {0.f, 0.f, 0.f, 0.f};   // rows 16-31 x cols 16-31
    // (tile 10 is the i>j mirror of 01 -> never needed)

    #pragma unroll
    for (int kc = 0; kc < 256; kc += 32) {
        const float4* p0 = (const float4*)(r0 + kc);
        const float4* p1 = (const float4*)(r1 + kc);
        float4 a0 = p0[0], a1 = p0[1];
        float4 b0 = p1[0], b1 = p1[1];

        bf16x8 f0, f1;
        f0[0] = f2bf(a0.x); f0[1] = f2bf(a0.y); f0[2] = f2bf(a0.z); f0[3] = f2bf(a0.w);
        f0[4] = f2bf(a1.x); f0[5] = f2bf(a1.y); f0[6] = f2bf(a1.z); f0[7] = f2bf(a1.w);
        f1[0] = f2bf(b0.x); f1[1] = f2bf(b0.y); f1[2] = f2bf(b0.z); f1[3] = f2bf(b0.w);
        f1[4] = f2bf(b1.x); f1[5] = f2bf(b1.y); f1[6] = f2bf(b1.z); f1[7] = f2bf(b1.w);

        // A-frag and B-frag of a gram share the same per-lane data.
        acc00 = __builtin_amdgcn_mfma_f32_16x16x32_bf16(f0, f0, acc00, 0, 0, 0);
        acc01 = __builtin_amdgcn_mfma_f32_16x16x32_bf16(f0, f1, acc01, 0, 0, 0);
        acc11 = __builtin_amdgcn_mfma_f32_16x16x32_bf16(f1, f1, acc11, 0, 0, 0);
    }

    // C/D layout (m89-verified): col = lane&15, row = (lane>>4)*4 + reg.
    // Diagonal of tiles 00/11: row==col -> reg = c - 4*q when in [0,4).
    const int dreg = c - 4 * q;
    if (dreg >= 0 && dreg < 4) {
        s_diag[c]      = acc00[dreg];   // ||u_c||^2
        s_diag[16 + c] = acc11[dreg];   // ||u_{16+c}||^2
    }
    __syncthreads();

    if (lane < 32) {
        float d = s_diag[lane];
        s_inv[lane] = 1.0f / fmaxf(sqrtf(d), EPS_NORM);
    }
    __syncthreads();

    const float invj0 = s_inv[c];
    const float invj1 = s_inv[16 + c];
    const int   sj0   = s_sch[c];
    const int   sj1   = s_sch[16 + c];

    float sum = 0.0f;
    #pragma unroll
    for (int r = 0; r < 4; ++r) {
        const int   i0    = q * 4 + r;
        const float inv_i = s_inv[i0];
        const int   si    = s_sch[i0];

        // tile 01: i = i0 (<16), j = 16+c  -> always i<j
        {
            float sim = acc01[r] * inv_i * invj1;
            sum += (si == sj1) ? (1.0f - sim) : fmaxf(sim - MARGIN, 0.0f);
        }
        if (i0 < c) {
            // tile 00: i = i0, j = c
            float sim = acc00[r] * inv_i * invj0;
            sum += (si == sj0) ? (1.0f - sim) : fmaxf(sim - MARGIN, 0.0f);
            // tile 11: i = 16+i0, j = 16+c
            float sim2 = acc11[r] * s_inv[16 + i0] * invj1;
            sum += (s_sch[16 + i0] == sj1) ? (1.0f - sim2)
                                           : fmaxf(sim2 - MARGIN, 0.0f);
        }
    }

    // wave-64 reduction
    #pragma unroll
    for (int off = 32; off > 0; off >>= 1)
        sum += __shfl_down(sum, off, 64);

    if (lane == 0)
        atomicAdd(out, sum * NPAIR_INV);
}

extern "C" void kernel_launch(void* const* d_in, const int* in_sizes, int n_in,
                              void* d_out, int out_size, void* d_ws, size_t ws_size,
                              hipStream_t stream) {
    const float* emb = (const float*)d_in[0];
    const int*   sch = (const int*)d_in[1];
    float*       out = (float*)d_out;

    hipMemsetAsync(out, 0, sizeof(float), stream);   // d_out is poisoned 0xAA
    rhyme_loss_kernel<<<dim3(4096), dim3(64), 0, stream>>>(emb, sch, out);
}